// Round 5
// baseline (678.843 us; speedup 1.0000x reference)
//
#include <hip/hip_runtime.h>
#include <hip/hip_bf16.h>

typedef __bf16 bf16x8 __attribute__((ext_vector_type(8)));
typedef __bf16 bf16x4 __attribute__((ext_vector_type(4)));
typedef float  floatx4 __attribute__((ext_vector_type(4)));

#define L_SEQ 4096

// ---------------- fp32 -> bf16 cast, 8 elems/thread ----------------
__global__ void cvt_bf16_kernel(const float* __restrict__ src,
                                __bf16* __restrict__ dst, int n8)
{
    int i = blockIdx.x * blockDim.x + threadIdx.x;
    if (i >= n8) return;
    const float4* s = (const float4*)src + (size_t)i * 2;
    float4 f0 = s[0], f1 = s[1];
    bf16x8 o;
    o[0] = (__bf16)f0.x; o[1] = (__bf16)f0.y; o[2] = (__bf16)f0.z; o[3] = (__bf16)f0.w;
    o[4] = (__bf16)f1.x; o[5] = (__bf16)f1.y; o[6] = (__bf16)f1.z; o[7] = (__bf16)f1.w;
    *((bf16x8*)dst + i) = o;
}

// ---------------- 3 weight transposes in one launch: dst[n][k] = (bf16)src[k][n] ----------------
__global__ void transpose_cvt3_kernel(const float* __restrict__ WQ,
                                      const float* __restrict__ WK,
                                      const float* __restrict__ WO,
                                      __bf16* __restrict__ Wqk,
                                      __bf16* __restrict__ Wo)
{
    const int z = blockIdx.z;
    const float* src = (z == 0) ? WQ : (z == 1) ? WK : WO;
    __bf16* dst = (z == 0) ? Wqk : (z == 1) ? (Wqk + (size_t)1024 * 1024) : Wo;

    __shared__ float tile[32][33];
    int tx = threadIdx.x & 31, ty = threadIdx.x >> 5;   // 32 x 8
    int n0 = blockIdx.x * 32, k0 = blockIdx.y * 32;
    #pragma unroll
    for (int i = 0; i < 32; i += 8)
        tile[ty + i][tx] = src[(size_t)(k0 + ty + i) * 1024 + n0 + tx];
    __syncthreads();
    #pragma unroll
    for (int i = 0; i < 32; i += 8)
        dst[(size_t)(n0 + ty + i) * 1024 + k0 + tx] = (__bf16)tile[tx][ty + i];
}

// ---------------- global-token projections, k-split x8 ----------------
__global__ void akv_part_kernel(const float* __restrict__ ax,
                                const float* __restrict__ Wk,
                                const float* __restrict__ Wv,
                                float* __restrict__ part)
{
    int b = blockIdx.x, kv = blockIdx.y, z = blockIdx.z;
    int n = threadIdx.x * 4;
    const float* W   = kv ? Wv : Wk;
    const float* axr = ax + (size_t)b * 1024 + z * 128;
    float4 acc = {0.f, 0.f, 0.f, 0.f};
    for (int k = 0; k < 128; ++k) {
        float a = axr[k];
        float4 w = *(const float4*)(W + (size_t)(z * 128 + k) * 1024 + n);
        acc.x = fmaf(a, w.x, acc.x);
        acc.y = fmaf(a, w.y, acc.y);
        acc.z = fmaf(a, w.z, acc.z);
        acc.w = fmaf(a, w.w, acc.w);
    }
    *(float4*)(part + (((size_t)(b * 2 + kv)) * 8 + z) * 1024 + n) = acc;
}

__global__ void akv_reduce_kernel(const float* __restrict__ part,
                                  const float* __restrict__ bk,
                                  const float* __restrict__ bv,
                                  float* __restrict__ akv)
{
    int b = blockIdx.x, kv = blockIdx.y;
    int n = threadIdx.x * 4;
    float4 acc = *(const float4*)((kv ? bv : bk) + n);
    #pragma unroll
    for (int z = 0; z < 8; ++z) {
        float4 p = *(const float4*)(part + (((size_t)(b * 2 + kv)) * 8 + z) * 1024 + n);
        acc.x += p.x; acc.y += p.y; acc.z += p.z; acc.w += p.w;
    }
    *(float4*)(akv + ((size_t)b * 2 + kv) * 1024 + n) = acc;
}

// =====================================================================================
// 256x256 8-phase bf16 GEMM (T2+T3+T4+T5) — unchanged from R4 (best: 544.4 us).
// =====================================================================================
#define GLDS(gp, lp) __builtin_amdgcn_global_load_lds(                              \
    (const __attribute__((address_space(1))) void*)(gp),                            \
    (__attribute__((address_space(3))) void*)(lp), 16, 0, 0)

#define STAGE_A(hi, kt, buf) do {                                                   \
    GLDS(A + aS[0][hi] + (size_t)(kt) * 64, smem + (buf) * 65536 + aD[0][hi]);      \
    GLDS(A + aS[1][hi] + (size_t)(kt) * 64, smem + (buf) * 65536 + aD[1][hi]);      \
} while (0)
#define STAGE_B(hi, kt, buf) do {                                                   \
    GLDS(Bt + bS[0][hi] + (size_t)(kt) * 64, smem + (buf) * 65536 + bD[0][hi]);     \
    GLDS(Bt + bS[1][hi] + (size_t)(kt) * 64, smem + (buf) * 65536 + bD[1][hi]);     \
} while (0)

#define RDA(cb, mi, kk) (*(const bf16x8*)(smem + (cb) + awoff + ((mi) << 11) + ((kk) << 10)))
#define RDB(cb, ni, kk) (*(const bf16x8*)(smem + (cb) + bwoff + ((ni) << 11) + ((kk) << 10)))
#define MFMA16(af, bfv, c) (c) = __builtin_amdgcn_mfma_f32_16x16x32_bf16((af), (bfv), (c), 0, 0, 0)

#define WAIT_LGKM0() do { asm volatile("s_waitcnt lgkmcnt(0)");                     \
    __builtin_amdgcn_sched_barrier(0); } while (0)
#define WAIT_VM(n) do { asm volatile("s_waitcnt vmcnt(" #n ")");                    \
    __builtin_amdgcn_sched_barrier(0); } while (0)
#define SBAR() do { __builtin_amdgcn_sched_barrier(0);                              \
    asm volatile("s_barrier" ::: "memory");                                         \
    __builtin_amdgcn_sched_barrier(0); } while (0)

template <int NT, bool OUT_F32>
__global__ __launch_bounds__(512, 2) void gemm256_kernel(
    const __bf16* __restrict__ A, const __bf16* __restrict__ Bt,
    const float* __restrict__ b0, const float* __restrict__ b1, int nsplit,
    void* __restrict__ Cp, int M, int N, int K)
{
    __shared__ __align__(16) char smem[131072];   // [buf:2][A|B][32 subtiles][1024B]

    const int bid = blockIdx.x;
    const int xcd = bid & 7, g = bid >> 3;
    const int s = g & 31, r = g >> 5;             // s: co-resident slot, r: round
    int mt, nt;
    if constexpr (NT == 8) {
        nt = ((xcd & 1) << 2) | (s & 3);
        mt = (r << 5) + ((xcd >> 1) << 3) + (s >> 2);
    } else {
        nt = s & 3;
        mt = (xcd << 4) + (r << 3) + (s >> 2);
    }
    const int m0 = mt << 8, n0 = nt << 8;

    const int tid  = threadIdx.x;
    const int wave = tid >> 6, lane = tid & 63;
    const int l15  = lane & 15, quad = lane >> 4;
    const int ntile = K >> 6;

    // ---- staging addresses ----
    const int rowin = lane >> 2;                                   // row within subtile
    const int colel = ((lane & 3) << 3) ^ (((lane >> 5) & 1) << 4); // inverse-swizzled col (elems)
    size_t aS[2][2], bS[2][2];
    int    aD[2][2], bD[2][2];
    #pragma unroll
    for (int hi = 0; hi < 2; ++hi) {
        const int rgA = (wave & 3) + ((wave >> 2) << 3) + hi * 4;
        const int rgB = ((wave >> 1) << 2) + (wave & 1) + hi * 2;
        #pragma unroll
        for (int c = 0; c < 2; ++c) {
            aS[c][hi] = (size_t)(m0 + rgA * 16 + rowin) * K + c * 32 + colel;
            aD[c][hi] = (rgA * 2 + c) << 10;
            bS[c][hi] = (size_t)(n0 + rgB * 16 + rowin) * K + c * 32 + colel;
            bD[c][hi] = 32768 + ((rgB * 2 + c) << 10);
        }
    }

    // ---- fragment ds_read offsets (swizzled) ----
    const int alane = (l15 << 6) + ((quad << 4) ^ (((l15 >> 3) & 1) << 5));
    const int awoff = (((wave >> 2) * 8) << 11) + alane;            // + mi<<11 + kk<<10
    const int bwoff = 32768 + (((wave & 3) * 4) << 11) + alane;     // + ni<<11 + kk<<10

    floatx4 acc[8][4] = {};

    // ---- prologue ----
    STAGE_A(0, 0, 0); STAGE_A(1, 0, 0); STAGE_B(0, 0, 0); STAGE_B(1, 0, 0);
    STAGE_A(0, 1, 1); STAGE_B(0, 1, 1); STAGE_B(1, 1, 1);
    WAIT_VM(6);
    SBAR();

    for (int t = 0; t < ntile; ++t) {
        const int p  = t & 1;
        const int cb = p * 65536;
        bf16x8 a0[4][2], a1[4][2], b0f[2][2], b1f[2][2];

        // ---------- phase 1 ----------
        #pragma unroll
        for (int mi = 0; mi < 4; ++mi) { a0[mi][0] = RDA(cb, mi, 0); a0[mi][1] = RDA(cb, mi, 1); }
        #pragma unroll
        for (int ni = 0; ni < 2; ++ni) { b0f[ni][0] = RDB(cb, ni, 0); b0f[ni][1] = RDB(cb, ni, 1); }
        if (t + 1 < ntile) STAGE_A(1, t + 1, p ^ 1);
        SBAR();
        WAIT_LGKM0();
        __builtin_amdgcn_s_setprio(1);
        #pragma unroll
        for (int mi = 0; mi < 4; ++mi)
            #pragma unroll
            for (int ni = 0; ni < 2; ++ni) {
                MFMA16(a0[mi][0], b0f[ni][0], acc[mi][ni]);
                MFMA16(a0[mi][1], b0f[ni][1], acc[mi][ni]);
            }
        __builtin_amdgcn_s_setprio(0);
        SBAR();

        // ---------- phase 2 ----------
        #pragma unroll
        for (int ni = 0; ni < 2; ++ni) { b1f[ni][0] = RDB(cb, ni + 2, 0); b1f[ni][1] = RDB(cb, ni + 2, 1); }
        if (t + 2 < ntile) STAGE_A(0, t + 2, p);
        SBAR();
        WAIT_LGKM0();
        __builtin_amdgcn_s_setprio(1);
        #pragma unroll
        for (int mi = 0; mi < 4; ++mi)
            #pragma unroll
            for (int ni = 0; ni < 2; ++ni) {
                MFMA16(a0[mi][0], b1f[ni][0], acc[mi][ni + 2]);
                MFMA16(a0[mi][1], b1f[ni][1], acc[mi][ni + 2]);
            }
        __builtin_amdgcn_s_setprio(0);
        SBAR();

        // ---------- phase 3 ----------
        #pragma unroll
        for (int mi = 0; mi < 4; ++mi) { a1[mi][0] = RDA(cb, mi + 4, 0); a1[mi][1] = RDA(cb, mi + 4, 1); }
        if (t + 2 < ntile) STAGE_B(0, t + 2, p);
        SBAR();
        WAIT_LGKM0();
        __builtin_amdgcn_s_setprio(1);
        #pragma unroll
        for (int mi = 0; mi < 4; ++mi)
            #pragma unroll
            for (int ni = 0; ni < 2; ++ni) {
                MFMA16(a1[mi][0], b1f[ni][0], acc[mi + 4][ni + 2]);
                MFMA16(a1[mi][1], b1f[ni][1], acc[mi + 4][ni + 2]);
            }
        __builtin_amdgcn_s_setprio(0);
        SBAR();

        // ---------- phase 4 ----------
        if (t + 2 < ntile) {
            STAGE_B(1, t + 2, p);
            WAIT_VM(6);
        } else {
            WAIT_VM(0);
        }
        SBAR();
        __builtin_amdgcn_s_setprio(1);
        #pragma unroll
        for (int mi = 0; mi < 4; ++mi)
            #pragma unroll
            for (int ni = 0; ni < 2; ++ni) {
                MFMA16(a1[mi][0], b0f[ni][0], acc[mi + 4][ni]);
                MFMA16(a1[mi][1], b0f[ni][1], acc[mi + 4][ni]);
            }
        __builtin_amdgcn_s_setprio(0);
        SBAR();
    }

    // ---- epilogue ----
    const int gmw = m0 + (wave >> 2) * 128;
    const int gnw = n0 + (wave & 3) * 64;
    #pragma unroll
    for (int ni = 0; ni < 4; ++ni) {
        int gn = gnw + ni * 16 + l15;
        float bv = (gn < nsplit) ? b0[gn] : b1[gn - nsplit];
        #pragma unroll
        for (int mi = 0; mi < 8; ++mi) {
            int gm = gmw + mi * 16 + quad * 4;
            #pragma unroll
            for (int r = 0; r < 4; ++r) {
                float v = acc[mi][ni][r] + bv;
                if constexpr (OUT_F32)
                    ((float*)Cp)[(size_t)(gm + r) * N + gn] = v;
                else
                    ((__bf16*)Cp)[(size_t)(gm + r) * N + gn] = (__bf16)v;
            }
        }
    }
}

// ---------------- attention v2: one thread per (token, head), zero cross-lane ops ----
// Thread (h = t>>4, i = t&15) owns all 64 dims of head h for token m = blk*16 + i.
// Scores: sA = q.ak, s0..s2 = q.k[m-1..m+1] (zero-padded rows give score 0 and V 0,
// matching the reference's pad semantics). Two streaming passes over the k rows
// (second pass L1-hit). No LDS, no shfl; straight-line FMA, 4 exp per thread.
__global__ __launch_bounds__(256) void attn_kernel(const __bf16* __restrict__ qk,
                                                   const float* __restrict__ akv,
                                                   __bf16* __restrict__ att)
{
    const int t = threadIdx.x;
    const int h = t >> 4;          // head 0..15
    const int i = t & 15;          // token within block
    const int m = blockIdx.x * 16 + i;   // 16 | 4096 -> block stays in one batch
    const int l = m & (L_SEQ - 1);
    const int b = m >> 12;

    const __bf16* qrow = qk + (size_t)m * 2048 + h * 64;
    const __bf16* krow = qk + (size_t)m * 2048 + 1024 + h * 64;   // k[m]
    const float*  akr  = akv + ((size_t)b * 2 + 0) * 1024 + h * 64;
    const float*  avr  = akv + ((size_t)b * 2 + 1) * 1024 + h * 64;
    const bool vm = (l >= 1), vp = (l <= L_SEQ - 2);

    float sA = 0.f, s0 = 0.f, s1 = 0.f, s2 = 0.f;
    #pragma unroll
    for (int c = 0; c < 8; ++c) {
        bf16x8 qc = *(const bf16x8*)(qrow + c * 8);
        bf16x8 k1 = *(const bf16x8*)(krow + c * 8);
        bf16x8 k0 = {}, k2 = {};
        if (vm) k0 = *(const bf16x8*)(krow - 2048 + c * 8);
        if (vp) k2 = *(const bf16x8*)(krow + 2048 + c * 8);
        float a[8];
        *(float4*)(a)     = *(const float4*)(akr + c * 8);
        *(float4*)(a + 4) = *(const float4*)(akr + c * 8 + 4);
        #pragma unroll
        for (int d = 0; d < 8; ++d) {
            float qd = (float)qc[d];
            sA = fmaf(qd, a[d], sA);
            s0 = fmaf(qd, (float)k0[d], s0);
            s1 = fmaf(qd, (float)k1[d], s1);
            s2 = fmaf(qd, (float)k2[d], s2);
        }
    }
    const float sc = 0.125f;   // 1/sqrt(64)
    sA *= sc; s0 *= sc; s1 *= sc; s2 *= sc;
    float mx = fmaxf(fmaxf(sA, s0), fmaxf(s1, s2));
    float eA = __expf(sA - mx), e0 = __expf(s0 - mx), e1 = __expf(s1 - mx), e2 = __expf(s2 - mx);
    float inv = 1.f / (eA + e0 + e1 + e2);
    eA *= inv; e0 *= inv; e1 *= inv; e2 *= inv;

    __bf16* orow = att + (size_t)m * 1024 + h * 64;
    #pragma unroll
    for (int c = 0; c < 8; ++c) {
        bf16x8 k1 = *(const bf16x8*)(krow + c * 8);
        bf16x8 k0 = {}, k2 = {};
        if (vm) k0 = *(const bf16x8*)(krow - 2048 + c * 8);
        if (vp) k2 = *(const bf16x8*)(krow + 2048 + c * 8);
        float a[8];
        *(float4*)(a)     = *(const float4*)(avr + c * 8);
        *(float4*)(a + 4) = *(const float4*)(avr + c * 8 + 4);
        bf16x8 o;
        #pragma unroll
        for (int d = 0; d < 8; ++d)
            o[d] = (__bf16)(eA * a[d] + e0 * (float)k0[d] + e1 * (float)k1[d] + e2 * (float)k2[d]);
        *(bf16x8*)(orow + c * 8) = o;
    }
}

extern "C" void kernel_launch(void* const* d_in, const int* in_sizes, int n_in,
                              void* d_out, int out_size, void* d_ws, size_t ws_size,
                              hipStream_t stream)
{
    const float* x    = (const float*)d_in[0];
    const float* ax   = (const float*)d_in[1];
    const float* WQ_w = (const float*)d_in[2];
    const float* WQ_b = (const float*)d_in[3];
    const float* WK_w = (const float*)d_in[4];
    const float* WK_b = (const float*)d_in[5];
    const float* WV_w = (const float*)d_in[6];
    const float* WV_b = (const float*)d_in[7];
    const float* WO_w = (const float*)d_in[8];
    const float* WO_b = (const float*)d_in[9];
    float* out = (float*)d_out;

    const int M = 8 * 4096;          // 32768 tokens

    // workspace layout
    char* ws = (char*)d_ws;
    __bf16* xb   = (__bf16*)(ws);                       //  67,108,864 B
    __bf16* Wqk  = (__bf16*)(ws + 67108864);            //   4,194,304 B  (2048 x 1024, N-major)
    __bf16* Wo   = (__bf16*)(ws + 71303168);            //   2,097,152 B  (1024 x 1024, N-major)
    __bf16* qk   = (__bf16*)(ws + 73400320);            // 134,217,728 B  (M x 2048)
    __bf16* att  = (__bf16*)(ws + 207618048);           //  67,108,864 B  (M x 1024)
    float*  akv  = (float*)(ws + 274726912);            //      65,536 B
    float*  akvp = (float*)(ws + 274792448);            //     524,288 B  (partials)

    // 1) x -> bf16
    {
        int n8 = (M * 1024) / 8;   // 4,194,304
        cvt_bf16_kernel<<<n8 / 256, 256, 0, stream>>>(x, xb, n8);
    }
    // 2) weight transpose+cast (one launch)
    transpose_cvt3_kernel<<<dim3(32, 32, 3), 256, 0, stream>>>(WQ_w, WK_w, WO_w, Wqk, Wo);
    // 3) global token projections (fp32), k-split + reduce
    akv_part_kernel<<<dim3(8, 2, 8), 256, 0, stream>>>(ax, WK_w, WV_w, akvp);
    akv_reduce_kernel<<<dim3(8, 2), 256, 0, stream>>>(akvp, WK_b, WV_b, akv);
    // 4) fused Q|K projection GEMM: (M x 2048) = xb @ [WQ|WK]; 256^2 8-phase, NT=8
    gemm256_kernel<8, false><<<(M / 256) * 8, 512, 0, stream>>>(
        xb, Wqk, WQ_b, WK_b, 1024, (void*)qk, M, 2048, 1024);
    // 5) attention -> att (bf16), one thread per (token, head)
    attn_kernel<<<M / 16, 256, 0, stream>>>(qk, akv, att);
    // 6) output projection: out (M x 1024 fp32) = att @ WO + WO_b; NT=4
    gemm256_kernel<4, true><<<(M / 256) * 4, 512, 0, stream>>>(
        att, Wo, WO_b, WO_b, 1024, (void*)out, M, 1024, 1024);
}